// Round 9
// baseline (613.570 us; speedup 1.0000x reference)
//
#include <hip/hip_runtime.h>
#include <cstdint>
#include <cstddef>

typedef short short8 __attribute__((ext_vector_type(8)));
typedef float floatx4 __attribute__((ext_vector_type(4)));
typedef unsigned short u16;

__device__ __forceinline__ u16 f2bf(float f) {
    unsigned u = __float_as_uint(f);
    u += 0x7FFFu + ((u >> 16) & 1u);
    return (u16)(u >> 16);
}
__device__ __forceinline__ float bf2f(u16 h) {
    return __uint_as_float(((unsigned)h) << 16);
}

// ---------------------------------------------------------------------------
// Kernel 1: x [4][72][32][32][32] f32 (NCDHW)  ->  xt [4][32][32][32][72] bf16
// ---------------------------------------------------------------------------
__global__ __launch_bounds__(256) void k_transpose_x(const float* __restrict__ x,
                                                     u16* __restrict__ xt) {
    __shared__ float tile[72 * 33];
    const int bx = blockIdx.x;               // ((b*32+d)*32+h)
    const int tid = threadIdx.x;
    const int b = bx >> 10, d = (bx >> 5) & 31, h = bx & 31;
    const float* src = x + (size_t)b * 72 * 32768 + d * 1024 + h * 32;
    for (int e = tid; e < 2304; e += 256) {
        int ci = e >> 5, w = e & 31;
        tile[ci * 33 + w] = src[(size_t)ci * 32768 + w];
    }
    __syncthreads();
    u16* dst = xt + (size_t)bx * 2304;
    for (int e = tid; e < 2304; e += 256) {
        int w = e / 72, ci = e - w * 72;
        dst[e] = f2bf(tile[ci * 33 + w]);
    }
}

// ---------------------------------------------------------------------------
// Kernel 2: W [176][72][5][5][5] f32 -> wt bf16 per-lane B-fragment layout:
//   wt[kd][kh][kblk(12)][nblk(11)][lane(64)][8]   (linear in kk = kh*12+kb)
//   k >= 360 tail is ZERO-FILLED (A-tail garbage must multiply 0).
// ---------------------------------------------------------------------------
__global__ __launch_bounds__(256) void k_prep_w(const float* __restrict__ W,
                                                u16* __restrict__ wt) {
    const int gid = blockIdx.x * 256 + threadIdx.x;   // 825*256 = 211200 = 3300 frags * 64
    const int frag = gid >> 6, lane = gid & 63;
    const int nb = frag % 11;
    int t = frag / 11;
    const int kb = t % 12;
    t = t / 12;
    const int kh = t % 5, kd = t / 5;
    const int n = lane & 15, q8 = (lane >> 4) * 8;
    const int co = nb * 16 + n;
    u16 v[8] __attribute__((aligned(16)));
    #pragma unroll
    for (int j = 0; j < 8; ++j) {
        int k = kb * 32 + q8 + j;
        u16 r = 0;
        if (k < 360) {
            int kw = k / 72, ci = k - kw * 72;
            r = f2bf(W[((size_t)co * 72 + ci) * 125 + kd * 25 + kh * 5 + kw]);
        }
        v[j] = r;
    }
    *(uint4*)(wt + (size_t)gid * 8) = *(const uint4*)v;
}

// ---------------------------------------------------------------------------
// Kernel 3: implicit-GEMM conv + fused gating, BARRIER-FREE inner loop.
// Grid 1024 = (b:4, d:32, ht:4, cb:2), XCD-swizzled. Block: 256 thr = 4 waves.
// Block tile: 8 h-rows x 32 w x co-half; wave: 2 h-rows x 32 w x co-half.
// Gate-self-contained co-split (validated round-5):
//   cb0: frags nb {0,1,2,3, 9}   NF=5 (acc 80 AGPR)
//   cb1: frags nb {4,5,6,7,8,10} NF=6 (acc 96 AGPR)
//  - A: staged in LDS once per kd. LP=2624 includes a 32-elem ZEROED tail
//    pad per row: the kb=11 fragment read reaches row-offset 2616 (k in
//    [360,384), weight=0) -- without the pad this read leaves sx and
//    0 x LDS-residue-NaN = NaN (round-8 failure).
//  - B: per-lane global loads (L2/L3-resident wt), 3-rotor register ring,
//    prefetch distance ~2 steps (~850 cyc issue-to-use >> L2 latency).
//    acc-halving frees the ~70 VGPRs this needs (rounds 2/4 spilled at 176).
//  - ZERO barriers in the 60-step loop (2 per kd for the A tile). Waves
//    drift; VM pipe streams B under MFMA; LDS carries only A reads.
// ---------------------------------------------------------------------------
#define LP 2624
#define MFMA_BF16 __builtin_amdgcn_mfma_f32_16x16x32_bf16

template<int CB>
__device__ __forceinline__ void conv_body(const u16* __restrict__ xt,
                                          const u16* __restrict__ wt,
                                          const float* __restrict__ scalar_bias,
                                          const float* __restrict__ gate_bias,
                                          u16* __restrict__ zt,
                                          u16* sx,
                                          int b, int d, int h0,
                                          int tid, int lane, int wv,
                                          int c15, int q) {
    constexpr int NF = CB ? 6 : 5;

    floatx4 acc[4][NF];
    #pragma unroll
    for (int i = 0; i < 4; ++i) {
        #pragma unroll
        for (int j = 0; j < NF; ++j) acc[i][j] = (floatx4){0.f, 0.f, 0.f, 0.f};
    }

    const int laneA = c15 * 72 + q * 8;
    short8 B0[NF], B1[NF], B2[NF];

    for (int kd = 0; kd < 5; ++kd) {
        const int dp = d + kd - 2;
        if (dp < 0 || dp >= 32) continue;            // block-uniform
        const u16* wt_kd = wt + (size_t)kd * 5 * 67584;   // 12*11*512 u16 per (kd,kh)

        __syncthreads();   // all waves done reading sx from previous kd-slice
        // ---- stage A d-slice into LDS (zero-fill halos, k-pad, tail pad) ----
        const u16* srcbase = xt + (size_t)((b * 32 + dp) * 32) * 2304;
        for (int idx = tid; idx < 12 * 328; idx += 256) {
            int r = idx / 328, c = idx - r * 328;
            int hp = h0 + r - 2;
            uint4 val = make_uint4(0u, 0u, 0u, 0u);
            if (hp >= 0 && hp < 32 && c >= 18 && c < 306)
                val = *(const uint4*)(srcbase + (size_t)hp * 2304 + (c * 8 - 144));
            *(uint4*)(&sx[r * LP + c * 8]) = val;
        }
        __syncthreads();   // sx visible

        auto bload = [&](short8 (&B)[NF], int kkn) {
            const u16* gp = wt_kd + (size_t)kkn * 5632 + lane * 8;
            #pragma unroll
            for (int f = 0; f < NF; ++f) {
                const int nb = CB ? ((f == 5) ? 10 : (f + 4)) : ((f == 4) ? 9 : f);
                B[f] = *(const short8*)(gp + nb * 512);
            }
        };

        int kh = 0, kb = 0;
        auto cstep = [&](short8 (&Bc)[NF], short8 (&Bn)[NF], int kkn) {
            bload(Bn, kkn);                      // prefetch, consumed ~2 steps later
            const u16* ap = sx + (2 * wv + kh) * LP + laneA + kb * 32;
            short8 A0 = *(const short8*)(ap);
            short8 A1 = *(const short8*)(ap + 1152);
            short8 A2 = *(const short8*)(ap + LP);
            short8 A3 = *(const short8*)(ap + LP + 1152);
            #pragma unroll
            for (int f = 0; f < NF; ++f) {
                acc[0][f] = MFMA_BF16(A0, Bc[f], acc[0][f], 0, 0, 0);
                acc[1][f] = MFMA_BF16(A1, Bc[f], acc[1][f], 0, 0, 0);
                acc[2][f] = MFMA_BF16(A2, Bc[f], acc[2][f], 0, 0, 0);
                acc[3][f] = MFMA_BF16(A3, Bc[f], acc[3][f], 0, 0, 0);
            }
            if (++kb == 12) { kb = 0; ++kh; }
        };

        bload(B0, 0);
        bload(B1, 1);
        #pragma unroll 1
        for (int kk = 0; kk < 60; kk += 3) {
            cstep(B0, B2, kk + 2 < 60 ? kk + 2 : 59);
            cstep(B1, B0, kk + 3 < 60 ? kk + 3 : 59);
            cstep(B2, B1, kk + 4 < 60 ? kk + 4 : 59);
        }
    }

    // ---- epilogue: fused gate + bf16 store to zt (validated round-5) ----
    // C/D layout: col(co within frag) = lane&15, row(pos) = q*4 + reg.
    constexpr int GF = NF - 1;                 // gate frag (nb 9 or 10)
    constexpr int NGATED = CB ? 5 : 3;
    int   slA[NGATED];
    float gbA[NGATED];
    #pragma unroll
    for (int j = 0; j < NGATED; ++j) {
        const int nb = CB ? (j + 4) : (j + 1);
        const int idx = (nb - 1) * 16 + c15;                 // co_f - 16
        const int mul = (nb <= 3) ? (idx / 3) : (16 + (idx - 48) / 5);
        slA[j] = (lane & 48) | (mul & 15);
        gbA[j] = gate_bias[mul];
    }
    const float sb = CB ? 0.f : scalar_bias[c15];
    #pragma unroll
    for (int mi = 0; mi < 4; ++mi) {
        const int hl = 2 * wv + (mi >> 1);
        const int wh = mi & 1;
        const size_t zrow0 = (size_t)((b * 32 + d) * 32 + (h0 + hl)) * 32;
        #pragma unroll
        for (int r = 0; r < 4; ++r) {
            const int w = wh * 16 + q * 4 + r;
            u16* zp = zt + (zrow0 + w) * 144;
            const float gv = acc[mi][GF][r];
            if (CB == 0)
                zp[c15] = f2bf(fmaxf(acc[mi][0][r] + sb, 0.f));  // scalar: relu+bias
            #pragma unroll
            for (int j = 0; j < NGATED; ++j) {
                const int nb = CB ? (j + 4) : (j + 1);
                float ys = __shfl(gv, slA[j], 64);
                float g  = 1.f / (1.f + __expf(-(ys + gbA[j])));
                zp[nb * 16 + c15] = f2bf(acc[mi][CB ? j : (j + 1)][r] * g);
            }
        }
    }
}

__global__ __launch_bounds__(256, 2) void k_conv(const u16* __restrict__ xt,
                                                 const u16* __restrict__ wt,
                                                 const float* __restrict__ scalar_bias,
                                                 const float* __restrict__ gate_bias,
                                                 u16* __restrict__ zt) {
    __shared__ __align__(16) u16 sx[12 * LP];    // 62,976 B -> 2 blocks/CU
    const int bx = blockIdx.x;
    // XCD swizzle (1024 = 8 XCD x 128, bijective); (cb,ht) fastest.
    const int swz = (bx & 7) * 128 + (bx >> 3);
    const int cb = swz & 1, ht = (swz >> 1) & 3, d = (swz >> 3) & 31, b = swz >> 8;
    const int h0 = ht * 8;
    const int tid = threadIdx.x, lane = tid & 63, wv = tid >> 6;
    const int c15 = lane & 15, q = lane >> 4;

    if (cb == 0)
        conv_body<0>(xt, wt, scalar_bias, gate_bias, zt, sx, b, d, h0, tid, lane, wv, c15, q);
    else
        conv_body<1>(xt, wt, scalar_bias, gate_bias, zt, sx, b, d, h0, tid, lane, wv, c15, q);
}

// ---------------------------------------------------------------------------
// Kernel 4a: separable Gaussian, h+w pass (stride 2 in h,w).
// zt [4][32][32][32][144] bf16 -> tmp [4][32][16][16][144] f32.
// (The reference 5x5x5 kernel is rank-1: g1 x g1 x g1.)
// Index space: b(4) x d(32) x oh(16) x ow(16) x c8(18) = 589,824 = 2304*256.
// ---------------------------------------------------------------------------
__global__ __launch_bounds__(256) void k_lowpass_wh(const u16* __restrict__ zt,
                                                    float* __restrict__ tmp) {
    const int gid = blockIdx.x * 256 + threadIdx.x;   // 2304*256 = 589,824
    const int c8 = gid % 18;
    int r = gid / 18;
    const int ow = r & 15; r >>= 4;
    const int oh = r & 15; r >>= 4;
    const int d = r & 31;
    const int b = r >> 5;
    const float lw[5] = {0.03208210f, 0.23705644f, 0.46172277f, 0.23705644f, 0.03208210f};
    float a[8];
    #pragma unroll
    for (int j = 0; j < 8; ++j) a[j] = 0.f;
    const u16* zb = zt + (size_t)((b * 32 + d) * 32) * 32 * 144 + c8 * 8;
    for (int kh = 0; kh < 5; ++kh) {
        const int hz = 2 * oh + kh - 2;
        if (hz < 0 || hz >= 32) continue;
        const u16* rowp = zb + (size_t)hz * 32 * 144;
        #pragma unroll
        for (int kw = 0; kw < 5; ++kw) {
            const int wz = 2 * ow + kw - 2;
            if (wz < 0 || wz >= 32) continue;
            const float wt2 = lw[kh] * lw[kw];
            u16 v[8] __attribute__((aligned(16)));
            *(uint4*)v = *(const uint4*)(rowp + (size_t)wz * 144);
            #pragma unroll
            for (int j = 0; j < 8; ++j) a[j] += wt2 * bf2f(v[j]);
        }
    }
    float* tp = tmp + (size_t)(((b * 32 + d) * 16 + oh) * 16 + ow) * 144 + c8 * 8;
    *(float4*)(tp)     = make_float4(a[0], a[1], a[2], a[3]);
    *(float4*)(tp + 4) = make_float4(a[4], a[5], a[6], a[7]);
}

// ---------------------------------------------------------------------------
// Kernel 4b: separable Gaussian, d pass (stride 2 in d) + NCDHW transpose.
// tmp [4][32][16][16][144] f32 -> out [4][144][16][16][16] f32.
// Each thread: one (b,c,od,oh), all 16 ow -> 64 B coalesced store.
// Index space: b(4) x c(144) x od(16) x oh(16) = 147,456 = 576*256.
// ---------------------------------------------------------------------------
__global__ __launch_bounds__(256) void k_lowpass_d(const float* __restrict__ tmp,
                                                   float* __restrict__ out) {
    const int gid = blockIdx.x * 256 + threadIdx.x;   // 576*256 = 147,456
    const int oh = gid & 15;
    int r = gid >> 4;
    const int od = r & 15; r >>= 4;
    const int c = r % 144;
    const int b = r / 144;
    const float lw[5] = {0.03208210f, 0.23705644f, 0.46172277f, 0.23705644f, 0.03208210f};
    float a[16];
    #pragma unroll
    for (int j = 0; j < 16; ++j) a[j] = 0.f;
    for (int kd = 0; kd < 5; ++kd) {
        const int dz = 2 * od + kd - 2;
        if (dz < 0 || dz >= 32) continue;
        const float w = lw[kd];
        const float* base = tmp + (size_t)(((b * 32 + dz) * 16 + oh) * 16) * 144 + c;
        #pragma unroll
        for (int ow = 0; ow < 16; ++ow) a[ow] += w * base[(size_t)ow * 144];
    }
    float* op = out + ((size_t)(b * 144 + c) * 4096) + od * 256 + oh * 16;
    #pragma unroll
    for (int ow = 0; ow < 16; ++ow) op[ow] = a[ow];
}

// ---------------------------------------------------------------------------
extern "C" void kernel_launch(void* const* d_in, const int* in_sizes, int n_in,
                              void* d_out, int out_size, void* d_ws, size_t ws_size,
                              hipStream_t stream) {
    const float* x  = (const float*)d_in[0];   // 4*72*32^3
    const float* W  = (const float*)d_in[1];   // 176*72*125
    const float* sb = (const float*)d_in[2];   // 16
    const float* gb = (const float*)d_in[3];   // 32
    float* out = (float*)d_out;                // 4*144*16^3 f32

    char* ws = (char*)d_ws;
    u16* xt = (u16*)(ws);                      // 18,874,368 B
    u16* wt = (u16*)(ws + 18874368);           //  3,379,200 B
    u16* zt = (u16*)(ws + 22253568);           // 37,748,736 B  (total ~60 MB)
    float* tmp = (float*)(ws);                 // reuses xt region after k_conv
                                               // (4*32*16*16*144*4 = 18,874,368 B, exact fit)

    hipLaunchKernelGGL(k_transpose_x, dim3(4096), dim3(256), 0, stream, x, xt);
    hipLaunchKernelGGL(k_prep_w,      dim3(825),  dim3(256), 0, stream, W, wt);
    hipLaunchKernelGGL(k_conv,        dim3(1024), dim3(256), 0, stream, xt, wt, sb, gb, zt);
    hipLaunchKernelGGL(k_lowpass_wh,  dim3(2304), dim3(256), 0, stream, zt, tmp);
    hipLaunchKernelGGL(k_lowpass_d,   dim3(576),  dim3(256), 0, stream, tmp, out);
}

// Round 10
// 532.613 us; speedup vs baseline: 1.1520x; 1.1520x over previous
//
#include <hip/hip_runtime.h>
#include <cstdint>
#include <cstddef>

typedef short short8 __attribute__((ext_vector_type(8)));
typedef float floatx4 __attribute__((ext_vector_type(4)));
typedef unsigned short u16;

__device__ __forceinline__ u16 f2bf(float f) {
    unsigned u = __float_as_uint(f);
    u += 0x7FFFu + ((u >> 16) & 1u);
    return (u16)(u >> 16);
}
__device__ __forceinline__ float bf2f(u16 h) {
    return __uint_as_float(((unsigned)h) << 16);
}

// async global->LDS, 16B per lane; LDS base must be wave-uniform.
__device__ __forceinline__ void gload_lds16(const u16* g, u16* l) {
    __builtin_amdgcn_global_load_lds(
        (const __attribute__((address_space(1))) void*)g,
        (__attribute__((address_space(3))) void*)l, 16, 0, 0);
}

// ---------------------------------------------------------------------------
// Kernel 1: x [4][72][32][32][32] f32 (NCDHW)  ->  xt [4][32][32][32][72] bf16
// ---------------------------------------------------------------------------
__global__ __launch_bounds__(256) void k_transpose_x(const float* __restrict__ x,
                                                     u16* __restrict__ xt) {
    __shared__ float tile[72 * 33];
    const int bx = blockIdx.x;               // ((b*32+d)*32+h)
    const int tid = threadIdx.x;
    const int b = bx >> 10, d = (bx >> 5) & 31, h = bx & 31;
    const float* src = x + (size_t)b * 72 * 32768 + d * 1024 + h * 32;
    for (int e = tid; e < 2304; e += 256) {
        int ci = e >> 5, w = e & 31;
        tile[ci * 33 + w] = src[(size_t)ci * 32768 + w];
    }
    __syncthreads();
    u16* dst = xt + (size_t)bx * 2304;
    for (int e = tid; e < 2304; e += 256) {
        int w = e / 72, ci = e - w * 72;
        dst[e] = f2bf(tile[ci * 33 + w]);
    }
}

// ---------------------------------------------------------------------------
// Kernel 2: W [176][72][5][5][5] f32 -> wt bf16 per-lane B-fragment layout:
//   wt[kd][kh][kblk(12)][nblk(11)][lane(64)][8]   (linear in kk = kh*12+kb)
//   k >= 360 tail is ZERO-FILLED.
// ---------------------------------------------------------------------------
__global__ __launch_bounds__(256) void k_prep_w(const float* __restrict__ W,
                                                u16* __restrict__ wt) {
    const int gid = blockIdx.x * 256 + threadIdx.x;   // 825*256 = 211200 = 3300 frags * 64
    const int frag = gid >> 6, lane = gid & 63;
    const int nb = frag % 11;
    int t = frag / 11;
    const int kb = t % 12;
    t = t / 12;
    const int kh = t % 5, kd = t / 5;
    const int n = lane & 15, q8 = (lane >> 4) * 8;
    const int co = nb * 16 + n;
    u16 v[8] __attribute__((aligned(16)));
    #pragma unroll
    for (int j = 0; j < 8; ++j) {
        int k = kb * 32 + q8 + j;
        u16 r = 0;
        if (k < 360) {
            int kw = k / 72, ci = k - kw * 72;
            r = f2bf(W[((size_t)co * 72 + ci) * 125 + kd * 25 + kh * 5 + kw]);
        }
        v[j] = r;
    }
    *(uint4*)(wt + (size_t)gid * 8) = *(const uint4*)v;
}

// ---------------------------------------------------------------------------
// Kernel 3: implicit-GEMM conv + fused gating (round-3 structure, 387 us,
// best measured) + bijective XCD swizzle.
// Grid 256 = (b:4, d:32, ht:2). Block: 512 threads = 8 waves.
// Block tile: 16 h-rows x 32 w x 176 co; wave: 2 h-rows x 32 w x 176 co.
// B (weights): 4-deep LDS ring, staged via global_load_lds with pair-cadence
// barriers: stages for pair P+1 are issued right AFTER pair P's barrier and
// drained at pair P+1's barrier -> the vmcnt(0) inside __syncthreads waits
// on loads issued a full pair (~6400 cyc) earlier: drain cost ~0.
// Disjointness: pair P reads bufs {2P,2P+1}%4, stages {2P+2,2P+3}%4.
// ---------------------------------------------------------------------------
#define LP 2624
#define MFMA_BF16 __builtin_amdgcn_mfma_f32_16x16x32_bf16

// Stage the two kb-steps s0_, s0_+1 into ring bufs (s0_)&3, (s0_+1)&3.
// 22 chunks of 1024B over 8 waves (waves 0..5 take a 3rd chunk).
#define STAGE_PAIR(s0_) do {                                                       \
    _Pragma("unroll")                                                              \
    for (int cc = 0; cc < 3; ++cc) {                                               \
        const int c_  = wv + cc * 8;                                               \
        const int st_ = (s0_) + (c_ >= 11 ? 1 : 0);                                \
        const int nb_ = (c_ >= 11) ? (c_ - 11) : c_;                               \
        if (c_ < 22 && st_ < 60)                                                   \
            gload_lds16(wt_kd + (size_t)st_ * 5632 + nb_ * 512 + lane * 8,         \
                        sB + (st_ & 3) * 5632 + nb_ * 512);                        \
    }                                                                              \
} while (0)

// One kb-step: 4 A-frag LDS reads + 11 B-frag LDS reads + 44 MFMAs.
#define CSTEP(aoff_, buf_) do {                                                    \
    const u16* ap_ = sxA + (aoff_);                                                \
    short8 A0_ = *(const short8*)(ap_);                                            \
    short8 A1_ = *(const short8*)(ap_ + 1152);                                     \
    short8 A2_ = *(const short8*)(ap_ + LP);                                       \
    short8 A3_ = *(const short8*)(ap_ + LP + 1152);                                \
    const u16* bb_ = sB + (buf_) * 5632 + lane * 8;                                \
    _Pragma("unroll")                                                              \
    for (int j = 0; j < 11; ++j) {                                                 \
        short8 bv = *(const short8*)(bb_ + j * 512);                               \
        acc[0][j] = MFMA_BF16(A0_, bv, acc[0][j], 0, 0, 0);                        \
        acc[1][j] = MFMA_BF16(A1_, bv, acc[1][j], 0, 0, 0);                        \
        acc[2][j] = MFMA_BF16(A2_, bv, acc[2][j], 0, 0, 0);                        \
        acc[3][j] = MFMA_BF16(A3_, bv, acc[3][j], 0, 0, 0);                        \
    }                                                                              \
} while (0)

__global__ __launch_bounds__(512, 2) void k_conv(const u16* __restrict__ xt,
                                                 const u16* __restrict__ wt,
                                                 const float* __restrict__ scalar_bias,
                                                 const float* __restrict__ gate_bias,
                                                 u16* __restrict__ zt) {
    __shared__ __align__(16) u16 sx[20 * LP];    // A tile: 16 out h-rows + 4 halo (104,960 B)
    __shared__ __align__(16) u16 sB[4 * 5632];   // B ring: 4 x 11,264 B = 45,056 B
    const int bx = blockIdx.x;
    // Bijective XCD swizzle (256 = 8 XCD x 32): each XCD gets a contiguous
    // (b,d,ht) range -> ~3 MB xt working set per XCD, L2-resident.
    const int swz = (bx & 7) * 32 + (bx >> 3);
    const int ht = swz & 1, d = (swz >> 1) & 31, b = swz >> 6;
    const int h0 = ht * 16;
    const int tid = threadIdx.x, lane = tid & 63, wv = tid >> 6;
    const int c15 = lane & 15, q = lane >> 4;

    floatx4 acc[4][11];
    #pragma unroll
    for (int i = 0; i < 4; ++i) {
        #pragma unroll
        for (int j = 0; j < 11; ++j) acc[i][j] = (floatx4){0.f, 0.f, 0.f, 0.f};
    }

    const int laneA = c15 * 72 + q * 8;
    const u16* sxA = &sx[2 * wv * LP + laneA];

    for (int kd = 0; kd < 5; ++kd) {
        const int dp = d + kd - 2;
        if (dp < 0 || dp >= 32) continue;            // block-uniform
        const u16* wt_kd = wt + (size_t)kd * 5 * 67584;   // 12*11*512 u16 per (kd,kh)

        __syncthreads();   // all waves done reading sx/sB from previous kd-slice
        // ---- stage A d-slice into LDS (zero-fill halos & k-pad region) ----
        const u16* srcbase = xt + (size_t)((b * 32 + dp) * 32) * 2304;
        for (int idx = tid; idx < 20 * 328; idx += 512) {
            int r = idx / 328, c = idx - r * 328;
            int hp = h0 + r - 2;
            uint4 val = make_uint4(0u, 0u, 0u, 0u);
            if (hp >= 0 && hp < 32 && c >= 18 && c < 306)
                val = *(const uint4*)(srcbase + (size_t)hp * 2304 + (c * 8 - 144));
            *(uint4*)(&sx[r * LP + c * 8]) = val;
        }
        STAGE_PAIR(0);     // steps 0,1 -> bufs 0,1
        __syncthreads();   // drains sx writes + first B pair (once per kd-slice)

        // ---- 60 kb-steps (kk = kh*12+kb), barrier every 2 steps ----
        int kh = 0, kb = 0;
        #pragma unroll 1
        for (int kp = 0; kp < 60; kp += 2) {
            if (kp) __syncthreads();   // drains stages issued one pair ago (free)
            STAGE_PAIR(kp + 2);        // next pair -> bufs (kp+2)&3, (kp+3)&3
            const int aoff = kh * LP + kb * 32;
            CSTEP(aoff,      kp & 3);
            CSTEP(aoff + 32, (kp + 1) & 3);
            kb += 2;
            if (kb == 12) { kb = 0; ++kh; }
        }
    }

    // ---- epilogue: fused gate + bf16 store to zt ----
    // C/D layout: col(co) = lane&15, row(pos) = q*4 + reg.
    const float sb = scalar_bias[c15];
    int   slA[9];
    float gbA[9];
    #pragma unroll
    for (int nb = 1; nb <= 8; ++nb) {
        int idx = (nb - 1) * 16 + c15;                       // co_f - 16
        int mul = (nb <= 3) ? (idx / 3) : (16 + (idx - 48) / 5);
        slA[nb] = (lane & 48) | (mul & 15);
        gbA[nb] = gate_bias[mul];
    }
    #pragma unroll
    for (int mi = 0; mi < 4; ++mi) {
        const int hl = 2 * wv + (mi >> 1);
        const int wh = mi & 1;
        const size_t zrow0 = (size_t)((b * 32 + d) * 32 + (h0 + hl)) * 32;
        #pragma unroll
        for (int r = 0; r < 4; ++r) {
            const int w = wh * 16 + q * 4 + r;
            u16* zp = zt + (zrow0 + w) * 144;
            zp[c15] = f2bf(fmaxf(acc[mi][0][r] + sb, 0.f));   // scalar field: relu+bias
            const float g9v  = acc[mi][9][r];
            const float g10v = acc[mi][10][r];
            #pragma unroll
            for (int nb = 1; nb <= 8; ++nb) {
                float ys = __shfl((nb <= 3) ? g9v : g10v, slA[nb], 64);
                float g  = 1.f / (1.f + __expf(-(ys + gbA[nb])));
                zp[nb * 16 + c15] = f2bf(acc[mi][nb][r] * g);
            }
        }
    }
}

// ---------------------------------------------------------------------------
// Kernel 4a: separable Gaussian, h+w pass (stride 2 in h,w).
// zt [4][32][32][32][144] bf16 -> tmp [4][32][16][16][144] f32.
// (The reference 5x5x5 kernel is rank-1: g1 x g1 x g1.)
// Index space: b(4) x d(32) x oh(16) x ow(16) x c8(18) = 589,824 = 2304*256.
// ---------------------------------------------------------------------------
__global__ __launch_bounds__(256) void k_lowpass_wh(const u16* __restrict__ zt,
                                                    float* __restrict__ tmp) {
    const int gid = blockIdx.x * 256 + threadIdx.x;   // 2304*256 = 589,824
    const int c8 = gid % 18;
    int r = gid / 18;
    const int ow = r & 15; r >>= 4;
    const int oh = r & 15; r >>= 4;
    const int d = r & 31;
    const int b = r >> 5;
    const float lw[5] = {0.03208210f, 0.23705644f, 0.46172277f, 0.23705644f, 0.03208210f};
    float a[8];
    #pragma unroll
    for (int j = 0; j < 8; ++j) a[j] = 0.f;
    const u16* zb = zt + (size_t)((b * 32 + d) * 32) * 32 * 144 + c8 * 8;
    for (int kh = 0; kh < 5; ++kh) {
        const int hz = 2 * oh + kh - 2;
        if (hz < 0 || hz >= 32) continue;
        const u16* rowp = zb + (size_t)hz * 32 * 144;
        #pragma unroll
        for (int kw = 0; kw < 5; ++kw) {
            const int wz = 2 * ow + kw - 2;
            if (wz < 0 || wz >= 32) continue;
            const float wt2 = lw[kh] * lw[kw];
            u16 v[8] __attribute__((aligned(16)));
            *(uint4*)v = *(const uint4*)(rowp + (size_t)wz * 144);
            #pragma unroll
            for (int j = 0; j < 8; ++j) a[j] += wt2 * bf2f(v[j]);
        }
    }
    float* tp = tmp + (size_t)(((b * 32 + d) * 16 + oh) * 16 + ow) * 144 + c8 * 8;
    *(float4*)(tp)     = make_float4(a[0], a[1], a[2], a[3]);
    *(float4*)(tp + 4) = make_float4(a[4], a[5], a[6], a[7]);
}

// ---------------------------------------------------------------------------
// Kernel 4b: separable Gaussian, d pass (stride 2 in d) + NCDHW transpose.
// tmp [4][32][16][16][144] f32 -> out [4][144][16][16][16] f32.
// Each thread: one (b,c,od,oh), all 16 ow -> 64 B coalesced store.
// Index space: b(4) x c(144) x od(16) x oh(16) = 147,456 = 576*256.
// ---------------------------------------------------------------------------
__global__ __launch_bounds__(256) void k_lowpass_d(const float* __restrict__ tmp,
                                                   float* __restrict__ out) {
    const int gid = blockIdx.x * 256 + threadIdx.x;   // 576*256 = 147,456
    const int oh = gid & 15;
    int r = gid >> 4;
    const int od = r & 15; r >>= 4;
    const int c = r % 144;
    const int b = r / 144;
    const float lw[5] = {0.03208210f, 0.23705644f, 0.46172277f, 0.23705644f, 0.03208210f};
    float a[16];
    #pragma unroll
    for (int j = 0; j < 16; ++j) a[j] = 0.f;
    for (int kd = 0; kd < 5; ++kd) {
        const int dz = 2 * od + kd - 2;
        if (dz < 0 || dz >= 32) continue;
        const float w = lw[kd];
        const float* base = tmp + (size_t)(((b * 32 + dz) * 16 + oh) * 16) * 144 + c;
        #pragma unroll
        for (int ow = 0; ow < 16; ++ow) a[ow] += w * base[(size_t)ow * 144];
    }
    float* op = out + ((size_t)(b * 144 + c) * 4096) + od * 256 + oh * 16;
    #pragma unroll
    for (int ow = 0; ow < 16; ++ow) op[ow] = a[ow];
}

// ---------------------------------------------------------------------------
extern "C" void kernel_launch(void* const* d_in, const int* in_sizes, int n_in,
                              void* d_out, int out_size, void* d_ws, size_t ws_size,
                              hipStream_t stream) {
    const float* x  = (const float*)d_in[0];   // 4*72*32^3
    const float* W  = (const float*)d_in[1];   // 176*72*125
    const float* sb = (const float*)d_in[2];   // 16
    const float* gb = (const float*)d_in[3];   // 32
    float* out = (float*)d_out;                // 4*144*16^3 f32

    char* ws = (char*)d_ws;
    u16* xt = (u16*)(ws);                      // 18,874,368 B
    u16* wt = (u16*)(ws + 18874368);           //  3,379,200 B
    u16* zt = (u16*)(ws + 22253568);           // 37,748,736 B  (total ~60 MB)
    float* tmp = (float*)(ws);                 // reuses xt region after k_conv
                                               // (4*32*16*16*144*4 = 18,874,368 B, exact fit)

    hipLaunchKernelGGL(k_transpose_x, dim3(4096), dim3(256), 0, stream, x, xt);
    hipLaunchKernelGGL(k_prep_w,      dim3(825),  dim3(256), 0, stream, W, wt);
    hipLaunchKernelGGL(k_conv,        dim3(256),  dim3(512), 0, stream, xt, wt, sb, gb, zt);
    hipLaunchKernelGGL(k_lowpass_wh,  dim3(2304), dim3(256), 0, stream, zt, tmp);
    hipLaunchKernelGGL(k_lowpass_d,   dim3(576),  dim3(256), 0, stream, tmp, out);
}

// Round 11
// 479.272 us; speedup vs baseline: 1.2802x; 1.1113x over previous
//
#include <hip/hip_runtime.h>
#include <cstdint>
#include <cstddef>

typedef short short8 __attribute__((ext_vector_type(8)));
typedef float floatx4 __attribute__((ext_vector_type(4)));
typedef unsigned short u16;

__device__ __forceinline__ u16 f2bf(float f) {
    unsigned u = __float_as_uint(f);
    u += 0x7FFFu + ((u >> 16) & 1u);
    return (u16)(u >> 16);
}
__device__ __forceinline__ float bf2f(u16 h) {
    return __uint_as_float(((unsigned)h) << 16);
}

// async global->LDS, 16B per lane; LDS base must be wave-uniform.
__device__ __forceinline__ void gload_lds16(const u16* g, u16* l) {
    __builtin_amdgcn_global_load_lds(
        (const __attribute__((address_space(1))) void*)g,
        (__attribute__((address_space(3))) void*)l, 16, 0, 0);
}

// ---------------------------------------------------------------------------
// Kernel 1: x [4][72][32][32][32] f32 (NCDHW)  ->  xt [4][32][32][32][72] bf16
// ---------------------------------------------------------------------------
__global__ __launch_bounds__(256) void k_transpose_x(const float* __restrict__ x,
                                                     u16* __restrict__ xt) {
    __shared__ float tile[72 * 33];
    const int bx = blockIdx.x;               // ((b*32+d)*32+h)
    const int tid = threadIdx.x;
    const int b = bx >> 10, d = (bx >> 5) & 31, h = bx & 31;
    const float* src = x + (size_t)b * 72 * 32768 + d * 1024 + h * 32;
    for (int e = tid; e < 2304; e += 256) {
        int ci = e >> 5, w = e & 31;
        tile[ci * 33 + w] = src[(size_t)ci * 32768 + w];
    }
    __syncthreads();
    u16* dst = xt + (size_t)bx * 2304;
    for (int e = tid; e < 2304; e += 256) {
        int w = e / 72, ci = e - w * 72;
        dst[e] = f2bf(tile[ci * 33 + w]);
    }
}

// ---------------------------------------------------------------------------
// Kernel 2: W [176][72][5][5][5] f32 -> wt bf16 per-lane B-fragment layout:
//   wt[kd][kh][kblk(12)][nblk(11)][lane(64)][8]   (linear in kk = kh*12+kb)
//   k >= 360 tail is ZERO-FILLED.
// ---------------------------------------------------------------------------
__global__ __launch_bounds__(256) void k_prep_w(const float* __restrict__ W,
                                                u16* __restrict__ wt) {
    const int gid = blockIdx.x * 256 + threadIdx.x;   // 825*256 = 211200 = 3300 frags * 64
    const int frag = gid >> 6, lane = gid & 63;
    const int nb = frag % 11;
    int t = frag / 11;
    const int kb = t % 12;
    t = t / 12;
    const int kh = t % 5, kd = t / 5;
    const int n = lane & 15, q8 = (lane >> 4) * 8;
    const int co = nb * 16 + n;
    u16 v[8] __attribute__((aligned(16)));
    #pragma unroll
    for (int j = 0; j < 8; ++j) {
        int k = kb * 32 + q8 + j;
        u16 r = 0;
        if (k < 360) {
            int kw = k / 72, ci = k - kw * 72;
            r = f2bf(W[((size_t)co * 72 + ci) * 125 + kd * 25 + kh * 5 + kw]);
        }
        v[j] = r;
    }
    *(uint4*)(wt + (size_t)gid * 8) = *(const uint4*)v;
}

// ---------------------------------------------------------------------------
// Kernel 3: implicit-GEMM conv + fused gating (round-10, 381.9 us verified).
// Grid 256 = (b:4, d:32, ht:2), bijective XCD swizzle. Block: 512 thr = 8 waves.
// Pair-cadence 4-slot LDS B-ring via global_load_lds: stages for pair P+1
// issued right after pair P's barrier, drained at pair P+1's barrier (free).
// ---------------------------------------------------------------------------
#define LP 2624
#define MFMA_BF16 __builtin_amdgcn_mfma_f32_16x16x32_bf16

#define STAGE_PAIR(s0_) do {                                                       \
    _Pragma("unroll")                                                              \
    for (int cc = 0; cc < 3; ++cc) {                                               \
        const int c_  = wv + cc * 8;                                               \
        const int st_ = (s0_) + (c_ >= 11 ? 1 : 0);                                \
        const int nb_ = (c_ >= 11) ? (c_ - 11) : c_;                               \
        if (c_ < 22 && st_ < 60)                                                   \
            gload_lds16(wt_kd + (size_t)st_ * 5632 + nb_ * 512 + lane * 8,         \
                        sB + (st_ & 3) * 5632 + nb_ * 512);                        \
    }                                                                              \
} while (0)

#define CSTEP(aoff_, buf_) do {                                                    \
    const u16* ap_ = sxA + (aoff_);                                                \
    short8 A0_ = *(const short8*)(ap_);                                            \
    short8 A1_ = *(const short8*)(ap_ + 1152);                                     \
    short8 A2_ = *(const short8*)(ap_ + LP);                                       \
    short8 A3_ = *(const short8*)(ap_ + LP + 1152);                                \
    const u16* bb_ = sB + (buf_) * 5632 + lane * 8;                                \
    _Pragma("unroll")                                                              \
    for (int j = 0; j < 11; ++j) {                                                 \
        short8 bv = *(const short8*)(bb_ + j * 512);                               \
        acc[0][j] = MFMA_BF16(A0_, bv, acc[0][j], 0, 0, 0);                        \
        acc[1][j] = MFMA_BF16(A1_, bv, acc[1][j], 0, 0, 0);                        \
        acc[2][j] = MFMA_BF16(A2_, bv, acc[2][j], 0, 0, 0);                        \
        acc[3][j] = MFMA_BF16(A3_, bv, acc[3][j], 0, 0, 0);                        \
    }                                                                              \
} while (0)

__global__ __launch_bounds__(512, 2) void k_conv(const u16* __restrict__ xt,
                                                 const u16* __restrict__ wt,
                                                 const float* __restrict__ scalar_bias,
                                                 const float* __restrict__ gate_bias,
                                                 u16* __restrict__ zt) {
    __shared__ __align__(16) u16 sx[20 * LP];    // A tile: 16 out h-rows + 4 halo (104,960 B)
    __shared__ __align__(16) u16 sB[4 * 5632];   // B ring: 4 x 11,264 B = 45,056 B
    const int bx = blockIdx.x;
    // Bijective XCD swizzle (256 = 8 XCD x 32): contiguous (b,d,ht) per XCD
    // -> ~3 MB xt working set per XCD, L2-resident (FETCH 66->24 MB measured).
    const int swz = (bx & 7) * 32 + (bx >> 3);
    const int ht = swz & 1, d = (swz >> 1) & 31, b = swz >> 6;
    const int h0 = ht * 16;
    const int tid = threadIdx.x, lane = tid & 63, wv = tid >> 6;
    const int c15 = lane & 15, q = lane >> 4;

    floatx4 acc[4][11];
    #pragma unroll
    for (int i = 0; i < 4; ++i) {
        #pragma unroll
        for (int j = 0; j < 11; ++j) acc[i][j] = (floatx4){0.f, 0.f, 0.f, 0.f};
    }

    const int laneA = c15 * 72 + q * 8;
    const u16* sxA = &sx[2 * wv * LP + laneA];

    for (int kd = 0; kd < 5; ++kd) {
        const int dp = d + kd - 2;
        if (dp < 0 || dp >= 32) continue;            // block-uniform
        const u16* wt_kd = wt + (size_t)kd * 5 * 67584;   // 12*11*512 u16 per (kd,kh)

        __syncthreads();   // all waves done reading sx/sB from previous kd-slice
        // ---- stage A d-slice into LDS (zero-fill halos & k-pad region) ----
        const u16* srcbase = xt + (size_t)((b * 32 + dp) * 32) * 2304;
        for (int idx = tid; idx < 20 * 328; idx += 512) {
            int r = idx / 328, c = idx - r * 328;
            int hp = h0 + r - 2;
            uint4 val = make_uint4(0u, 0u, 0u, 0u);
            if (hp >= 0 && hp < 32 && c >= 18 && c < 306)
                val = *(const uint4*)(srcbase + (size_t)hp * 2304 + (c * 8 - 144));
            *(uint4*)(&sx[r * LP + c * 8]) = val;
        }
        STAGE_PAIR(0);     // steps 0,1 -> bufs 0,1
        __syncthreads();   // drains sx writes + first B pair (once per kd-slice)

        // ---- 60 kb-steps (kk = kh*12+kb), barrier every 2 steps ----
        int kh = 0, kb = 0;
        #pragma unroll 1
        for (int kp = 0; kp < 60; kp += 2) {
            if (kp) __syncthreads();   // drains stages issued one pair ago (free)
            STAGE_PAIR(kp + 2);        // next pair -> bufs (kp+2)&3, (kp+3)&3
            const int aoff = kh * LP + kb * 32;
            CSTEP(aoff,      kp & 3);
            CSTEP(aoff + 32, (kp + 1) & 3);
            kb += 2;
            if (kb == 12) { kb = 0; ++kh; }
        }
    }

    // ---- epilogue: fused gate + bf16 store to zt ----
    // C/D layout: col(co) = lane&15, row(pos) = q*4 + reg.
    const float sb = scalar_bias[c15];
    int   slA[9];
    float gbA[9];
    #pragma unroll
    for (int nb = 1; nb <= 8; ++nb) {
        int idx = (nb - 1) * 16 + c15;                       // co_f - 16
        int mul = (nb <= 3) ? (idx / 3) : (16 + (idx - 48) / 5);
        slA[nb] = (lane & 48) | (mul & 15);
        gbA[nb] = gate_bias[mul];
    }
    #pragma unroll
    for (int mi = 0; mi < 4; ++mi) {
        const int hl = 2 * wv + (mi >> 1);
        const int wh = mi & 1;
        const size_t zrow0 = (size_t)((b * 32 + d) * 32 + (h0 + hl)) * 32;
        #pragma unroll
        for (int r = 0; r < 4; ++r) {
            const int w = wh * 16 + q * 4 + r;
            u16* zp = zt + (zrow0 + w) * 144;
            zp[c15] = f2bf(fmaxf(acc[mi][0][r] + sb, 0.f));   // scalar field: relu+bias
            const float g9v  = acc[mi][9][r];
            const float g10v = acc[mi][10][r];
            #pragma unroll
            for (int nb = 1; nb <= 8; ++nb) {
                float ys = __shfl((nb <= 3) ? g9v : g10v, slA[nb], 64);
                float g  = 1.f / (1.f + __expf(-(ys + gbA[nb])));
                zp[nb * 16 + c15] = f2bf(acc[mi][nb][r] * g);
            }
        }
    }
}

// ---------------------------------------------------------------------------
// Kernel 4a: separable Gaussian, d+h pass (stride 2 in d,h; w untouched).
// zt [4][32][32][32][144] bf16 -> tmp [b][od16][oh16][w32][144] f32.
// Index space: b(4) x od(16) x oh(16) x w(32) x c8(18) = 589,824 = 2304*256.
// gid%18 ordering => every wave's loads AND stores are contiguous 1024B
// (144 = 18 x 8-elem chunks tile a row exactly).
// ---------------------------------------------------------------------------
__global__ __launch_bounds__(256) void k_lowpass_dh(const u16* __restrict__ zt,
                                                    float* __restrict__ tmp) {
    const int gid = blockIdx.x * 256 + threadIdx.x;   // 2304*256 = 589,824
    const int c8 = gid % 18;
    int r = gid / 18;
    const int w  = r & 31; r >>= 5;
    const int oh = r & 15; r >>= 4;
    const int od = r & 15; r >>= 4;
    const int b  = r;
    const float lw[5] = {0.03208210f, 0.23705644f, 0.46172277f, 0.23705644f, 0.03208210f};
    float a[8];
    #pragma unroll
    for (int j = 0; j < 8; ++j) a[j] = 0.f;
    for (int kd = 0; kd < 5; ++kd) {
        const int dz = 2 * od + kd - 2;
        if (dz < 0 || dz >= 32) continue;
        for (int kh = 0; kh < 5; ++kh) {
            const int hz = 2 * oh + kh - 2;
            if (hz < 0 || hz >= 32) continue;
            const float wt2 = lw[kd] * lw[kh];
            const u16* p = zt + ((size_t)((b * 32 + dz) * 32 + hz) * 32 + w) * 144 + c8 * 8;
            u16 v[8] __attribute__((aligned(16)));
            *(uint4*)v = *(const uint4*)p;
            #pragma unroll
            for (int j = 0; j < 8; ++j) a[j] += wt2 * bf2f(v[j]);
        }
    }
    float* tp = tmp + ((size_t)(((b * 16 + od) * 16 + oh) * 32) + w) * 144 + c8 * 8;
    *(float4*)(tp)     = make_float4(a[0], a[1], a[2], a[3]);
    *(float4*)(tp + 4) = make_float4(a[4], a[5], a[6], a[7]);
}

// ---------------------------------------------------------------------------
// Kernel 4b: separable Gaussian, w pass (stride 2) + NCDHW transpose store.
// tmp [b][od][oh][w32][144] f32 -> out [4][144][16][16][16] f32.
// Reads are 288B runs; output uses the proven scattered-4B-store pattern
// (9.4 MB total). Index: b(4) x od(16) x oh(16) x ow(16) x c8(18) = 294,912.
// ---------------------------------------------------------------------------
__global__ __launch_bounds__(256) void k_lowpass_w(const float* __restrict__ tmp,
                                                   float* __restrict__ out) {
    const int gid = blockIdx.x * 256 + threadIdx.x;   // 1152*256 = 294,912
    const int c8 = gid % 18;
    int r = gid / 18;
    const int ow = r & 15; r >>= 4;
    const int oh = r & 15; r >>= 4;
    const int od = r & 15; r >>= 4;
    const int b  = r;
    const float lw[5] = {0.03208210f, 0.23705644f, 0.46172277f, 0.23705644f, 0.03208210f};
    float a[8];
    #pragma unroll
    for (int j = 0; j < 8; ++j) a[j] = 0.f;
    const float* tb = tmp + ((size_t)(((b * 16 + od) * 16 + oh) * 32)) * 144 + c8 * 8;
    #pragma unroll
    for (int kw = 0; kw < 5; ++kw) {
        const int wz = 2 * ow + kw - 2;
        if (wz < 0 || wz >= 32) continue;
        const float wt1 = lw[kw];
        const float* p = tb + (size_t)wz * 144;
        float4 v0 = *(const float4*)(p);
        float4 v1 = *(const float4*)(p + 4);
        a[0] += wt1 * v0.x; a[1] += wt1 * v0.y; a[2] += wt1 * v0.z; a[3] += wt1 * v0.w;
        a[4] += wt1 * v1.x; a[5] += wt1 * v1.y; a[6] += wt1 * v1.z; a[7] += wt1 * v1.w;
    }
    const int c0 = c8 * 8;
    float* op = out + ((size_t)b * 144 + c0) * 4096 + od * 256 + oh * 16 + ow;
    #pragma unroll
    for (int j = 0; j < 8; ++j) op[(size_t)j * 4096] = a[j];
}

// ---------------------------------------------------------------------------
extern "C" void kernel_launch(void* const* d_in, const int* in_sizes, int n_in,
                              void* d_out, int out_size, void* d_ws, size_t ws_size,
                              hipStream_t stream) {
    const float* x  = (const float*)d_in[0];   // 4*72*32^3
    const float* W  = (const float*)d_in[1];   // 176*72*125
    const float* sb = (const float*)d_in[2];   // 16
    const float* gb = (const float*)d_in[3];   // 32
    float* out = (float*)d_out;                // 4*144*16^3 f32

    char* ws = (char*)d_ws;
    u16* xt = (u16*)(ws);                      // 18,874,368 B
    u16* wt = (u16*)(ws + 18874368);           //  3,379,200 B
    u16* zt = (u16*)(ws + 22253568);           // 37,748,736 B  (total ~60 MB)
    float* tmp = (float*)(ws);                 // reuses xt region after k_conv
                                               // (4*16*16*32*144*4 = 18,874,368 B, exact fit)

    hipLaunchKernelGGL(k_transpose_x, dim3(4096), dim3(256), 0, stream, x, xt);
    hipLaunchKernelGGL(k_prep_w,      dim3(825),  dim3(256), 0, stream, W, wt);
    hipLaunchKernelGGL(k_conv,        dim3(256),  dim3(512), 0, stream, xt, wt, sb, gb, zt);
    hipLaunchKernelGGL(k_lowpass_dh,  dim3(2304), dim3(256), 0, stream, zt, tmp);
    hipLaunchKernelGGL(k_lowpass_w,   dim3(1152), dim3(256), 0, stream, tmp, out);
}

// Round 12
// 465.865 us; speedup vs baseline: 1.3171x; 1.0288x over previous
//
#include <hip/hip_runtime.h>
#include <cstdint>
#include <cstddef>

typedef short short8 __attribute__((ext_vector_type(8)));
typedef float floatx4 __attribute__((ext_vector_type(4)));
typedef unsigned short u16;

__device__ __forceinline__ u16 f2bf(float f) {
    unsigned u = __float_as_uint(f);
    u += 0x7FFFu + ((u >> 16) & 1u);
    return (u16)(u >> 16);
}
__device__ __forceinline__ float bf2f(u16 h) {
    return __uint_as_float(((unsigned)h) << 16);
}

// async global->LDS, 16B per lane; LDS base must be wave-uniform.
__device__ __forceinline__ void gload_lds16(const u16* g, u16* l) {
    __builtin_amdgcn_global_load_lds(
        (const __attribute__((address_space(1))) void*)g,
        (__attribute__((address_space(3))) void*)l, 16, 0, 0);
}

// ---------------------------------------------------------------------------
// Kernel 1: x [4][72][32][32][32] f32 (NCDHW)  ->  xt [4][32][32][32][72] bf16
// ---------------------------------------------------------------------------
__global__ __launch_bounds__(256) void k_transpose_x(const float* __restrict__ x,
                                                     u16* __restrict__ xt) {
    __shared__ float tile[72 * 33];
    const int bx = blockIdx.x;               // ((b*32+d)*32+h)
    const int tid = threadIdx.x;
    const int b = bx >> 10, d = (bx >> 5) & 31, h = bx & 31;
    const float* src = x + (size_t)b * 72 * 32768 + d * 1024 + h * 32;
    for (int e = tid; e < 2304; e += 256) {
        int ci = e >> 5, w = e & 31;
        tile[ci * 33 + w] = src[(size_t)ci * 32768 + w];
    }
    __syncthreads();
    u16* dst = xt + (size_t)bx * 2304;
    for (int e = tid; e < 2304; e += 256) {
        int w = e / 72, ci = e - w * 72;
        dst[e] = f2bf(tile[ci * 33 + w]);
    }
}

// ---------------------------------------------------------------------------
// Kernel 2: W [176][72][5][5][5] f32 -> wt bf16 per-lane B-fragment layout:
//   wt[kd][kh][kblk(12)][nblk(11)][lane(64)][8]   (linear in kk = kh*12+kb)
//   k >= 360 tail is ZERO-FILLED (A-tail garbage must multiply 0).
// ---------------------------------------------------------------------------
__global__ __launch_bounds__(256) void k_prep_w(const float* __restrict__ W,
                                                u16* __restrict__ wt) {
    const int gid = blockIdx.x * 256 + threadIdx.x;   // 825*256 = 211200 = 3300 frags * 64
    const int frag = gid >> 6, lane = gid & 63;
    const int nb = frag % 11;
    int t = frag / 11;
    const int kb = t % 12;
    t = t / 12;
    const int kh = t % 5, kd = t / 5;
    const int n = lane & 15, q8 = (lane >> 4) * 8;
    const int co = nb * 16 + n;
    u16 v[8] __attribute__((aligned(16)));
    #pragma unroll
    for (int j = 0; j < 8; ++j) {
        int k = kb * 32 + q8 + j;
        u16 r = 0;
        if (k < 360) {
            int kw = k / 72, ci = k - kw * 72;
            r = f2bf(W[((size_t)co * 72 + ci) * 125 + kd * 25 + kh * 5 + kw]);
        }
        v[j] = r;
    }
    *(uint4*)(wt + (size_t)gid * 8) = *(const uint4*)v;
}

// ---------------------------------------------------------------------------
// Kernel 3: implicit-GEMM conv + fused gating, TWO 4-wave barrier domains/CU.
// Grid 512 = (b:4, d:32, ht:4), bijective 8x64 XCD swizzle. Block: 256 thr.
// Block tile: 8 h-rows x 32 w x 176 co; wave: 2 h-rows x 32 w x 176 co
// (acc = 176 AGPR, same as the verified R10 epilogue/layout).
// LDS = 80,640 B exactly -> 2 blocks/CU. The two co-resident blocks have
// independent barrier phases: one block's 52-read LDS burst overlaps the
// other's MFMA burst (R10's single 8-wave domain measured wall = LDS+MFMA
// SUM, 6266 cyc/pair; overlap target ~max).
// Squeeze: LP=2592 (kb=11 tail overread <=24 elem lands in sB = finite
// weights, single smem allocation guarantees adjacency; R5-proven pitch);
// B-ring = 2 step-slots x 9 frags via global_load_lds (stage k+1 right
// after barrier k, drained at barrier k+1, ~1-2k cyc window >> L2 latency);
// frags 9,10 (gate columns) read per-wave from L2-resident wt.
// ---------------------------------------------------------------------------
#define LP 2592
#define MFMA_BF16 __builtin_amdgcn_mfma_f32_16x16x32_bf16

// Stage the 9 LDS-resident B frags (nb 0..8) of step kk_ into ring slot slot_.
#define STAGE(kk_, slot_) do {                                                     \
    const u16* gs_ = wt_kd + (size_t)(kk_) * 5632 + lane * 8;                      \
    u16* ds_ = sB + (slot_) * 4608;                                                \
    gload_lds16(gs_ + wv * 512, ds_ + wv * 512);                                   \
    gload_lds16(gs_ + (wv + 4) * 512, ds_ + (wv + 4) * 512);                       \
    if (wv == 0) gload_lds16(gs_ + 8 * 512, ds_ + 8 * 512);                        \
} while (0)

__global__ __launch_bounds__(256, 2) void k_conv(const u16* __restrict__ xt,
                                                 const u16* __restrict__ wt,
                                                 const float* __restrict__ scalar_bias,
                                                 const float* __restrict__ gate_bias,
                                                 u16* __restrict__ zt) {
    // Single allocation: sx (12 x LP) immediately followed by sB, so the
    // benign kb=11 tail overread stays inside finite bf16 data.
    __shared__ __align__(16) u16 smem[12 * LP + 2 * 4608];   // 80,640 B
    u16* sx = smem;
    u16* sB = smem + 12 * LP;
    const int bx = blockIdx.x;
    const int swz = (bx & 7) * 64 + (bx >> 3);   // 512 = 8 XCD x 64, bijective
    const int ht = swz & 3, d = (swz >> 2) & 31, b = swz >> 7;
    const int h0 = ht * 8;
    const int tid = threadIdx.x, lane = tid & 63, wv = tid >> 6;   // 4 waves
    const int c15 = lane & 15, q = lane >> 4;

    floatx4 acc[4][11];
    #pragma unroll
    for (int i = 0; i < 4; ++i) {
        #pragma unroll
        for (int j = 0; j < 11; ++j) acc[i][j] = (floatx4){0.f, 0.f, 0.f, 0.f};
    }

    const int laneA = c15 * 72 + q * 8;
    const u16* sxA = sx + 2 * wv * LP + laneA;

    for (int kd = 0; kd < 5; ++kd) {
        const int dp = d + kd - 2;
        if (dp < 0 || dp >= 32) continue;            // block-uniform
        const u16* wt_kd = wt + (size_t)kd * 5 * 67584;   // 12*11*512 u16 per (kd,kh)

        __syncthreads();   // all waves done with prev kd's sx/sB
        // ---- stage A d-slice into LDS (zero-fill halos & k-pad region) ----
        const u16* srcbase = xt + (size_t)((b * 32 + dp) * 32) * 2304;
        for (int idx = tid; idx < 12 * 324; idx += 256) {
            int r = idx / 324, c = idx - r * 324;
            int hp = h0 + r - 2;
            uint4 val = make_uint4(0u, 0u, 0u, 0u);
            if (hp >= 0 && hp < 32 && c >= 18 && c < 306)
                val = *(const uint4*)(srcbase + (size_t)hp * 2304 + (c * 8 - 144));
            *(uint4*)(&sx[r * LP + c * 8]) = val;
        }
        STAGE(0, 0);
        __syncthreads();   // sx + slot 0 ready

        // ---- 60 kb-steps, 2-slot ring, barrier per step ----
        int kh = 0, kb = 0;
        #pragma unroll 1
        for (int kk = 0; kk < 60; ++kk) {
            if (kk) __syncthreads();   // drains stage issued one step ago (free)
            if (kk < 59) STAGE(kk + 1, (kk + 1) & 1);   // issue-early
            const u16* gB_ = wt_kd + (size_t)kk * 5632 + lane * 8;
            short8 B9  = *(const short8*)(gB_ + 9 * 512);    // gate frags: L2 direct
            short8 B10 = *(const short8*)(gB_ + 10 * 512);
            const u16* ap = sxA + kh * LP + kb * 32;
            short8 A0 = *(const short8*)(ap);
            short8 A1 = *(const short8*)(ap + 1152);
            short8 A2 = *(const short8*)(ap + LP);
            short8 A3 = *(const short8*)(ap + LP + 1152);
            const u16* bb = sB + (kk & 1) * 4608 + lane * 8;
            __builtin_amdgcn_s_setprio(1);
            #pragma unroll
            for (int j = 0; j < 9; ++j) {
                short8 bv = *(const short8*)(bb + j * 512);
                acc[0][j] = MFMA_BF16(A0, bv, acc[0][j], 0, 0, 0);
                acc[1][j] = MFMA_BF16(A1, bv, acc[1][j], 0, 0, 0);
                acc[2][j] = MFMA_BF16(A2, bv, acc[2][j], 0, 0, 0);
                acc[3][j] = MFMA_BF16(A3, bv, acc[3][j], 0, 0, 0);
            }
            acc[0][9]  = MFMA_BF16(A0, B9,  acc[0][9],  0, 0, 0);
            acc[1][9]  = MFMA_BF16(A1, B9,  acc[1][9],  0, 0, 0);
            acc[2][9]  = MFMA_BF16(A2, B9,  acc[2][9],  0, 0, 0);
            acc[3][9]  = MFMA_BF16(A3, B9,  acc[3][9],  0, 0, 0);
            acc[0][10] = MFMA_BF16(A0, B10, acc[0][10], 0, 0, 0);
            acc[1][10] = MFMA_BF16(A1, B10, acc[1][10], 0, 0, 0);
            acc[2][10] = MFMA_BF16(A2, B10, acc[2][10], 0, 0, 0);
            acc[3][10] = MFMA_BF16(A3, B10, acc[3][10], 0, 0, 0);
            __builtin_amdgcn_s_setprio(0);
            if (++kb == 12) { kb = 0; ++kh; }
        }
    }

    // ---- epilogue: fused gate + bf16 store to zt (byte-identical to R10) ----
    // C/D layout: col(co) = lane&15, row(pos) = q*4 + reg.
    const float sb = scalar_bias[c15];
    int   slA[9];
    float gbA[9];
    #pragma unroll
    for (int nb = 1; nb <= 8; ++nb) {
        int idx = (nb - 1) * 16 + c15;                       // co_f - 16
        int mul = (nb <= 3) ? (idx / 3) : (16 + (idx - 48) / 5);
        slA[nb] = (lane & 48) | (mul & 15);
        gbA[nb] = gate_bias[mul];
    }
    #pragma unroll
    for (int mi = 0; mi < 4; ++mi) {
        const int hl = 2 * wv + (mi >> 1);
        const int wh = mi & 1;
        const size_t zrow0 = (size_t)((b * 32 + d) * 32 + (h0 + hl)) * 32;
        #pragma unroll
        for (int r = 0; r < 4; ++r) {
            const int w = wh * 16 + q * 4 + r;
            u16* zp = zt + (zrow0 + w) * 144;
            zp[c15] = f2bf(fmaxf(acc[mi][0][r] + sb, 0.f));   // scalar field: relu+bias
            const float g9v  = acc[mi][9][r];
            const float g10v = acc[mi][10][r];
            #pragma unroll
            for (int nb = 1; nb <= 8; ++nb) {
                float ys = __shfl((nb <= 3) ? g9v : g10v, slA[nb], 64);
                float g  = 1.f / (1.f + __expf(-(ys + gbA[nb])));
                zp[nb * 16 + c15] = f2bf(acc[mi][nb][r] * g);
            }
        }
    }
}

// ---------------------------------------------------------------------------
// Kernel 4a: separable Gaussian, d+h pass (stride 2 in d,h; w untouched).
// zt [4][32][32][32][144] bf16 -> tmp [b][od16][oh16][w32][144] f32.
// Index space: b(4) x od(16) x oh(16) x w(32) x c8(18) = 589,824 = 2304*256.
// ---------------------------------------------------------------------------
__global__ __launch_bounds__(256) void k_lowpass_dh(const u16* __restrict__ zt,
                                                    float* __restrict__ tmp) {
    const int gid = blockIdx.x * 256 + threadIdx.x;   // 2304*256 = 589,824
    const int c8 = gid % 18;
    int r = gid / 18;
    const int w  = r & 31; r >>= 5;
    const int oh = r & 15; r >>= 4;
    const int od = r & 15; r >>= 4;
    const int b  = r;
    const float lw[5] = {0.03208210f, 0.23705644f, 0.46172277f, 0.23705644f, 0.03208210f};
    float a[8];
    #pragma unroll
    for (int j = 0; j < 8; ++j) a[j] = 0.f;
    for (int kd = 0; kd < 5; ++kd) {
        const int dz = 2 * od + kd - 2;
        if (dz < 0 || dz >= 32) continue;
        for (int kh = 0; kh < 5; ++kh) {
            const int hz = 2 * oh + kh - 2;
            if (hz < 0 || hz >= 32) continue;
            const float wt2 = lw[kd] * lw[kh];
            const u16* p = zt + ((size_t)((b * 32 + dz) * 32 + hz) * 32 + w) * 144 + c8 * 8;
            u16 v[8] __attribute__((aligned(16)));
            *(uint4*)v = *(const uint4*)p;
            #pragma unroll
            for (int j = 0; j < 8; ++j) a[j] += wt2 * bf2f(v[j]);
        }
    }
    float* tp = tmp + ((size_t)(((b * 16 + od) * 16 + oh) * 32) + w) * 144 + c8 * 8;
    *(float4*)(tp)     = make_float4(a[0], a[1], a[2], a[3]);
    *(float4*)(tp + 4) = make_float4(a[4], a[5], a[6], a[7]);
}

// ---------------------------------------------------------------------------
// Kernel 4b: separable Gaussian, w pass (stride 2) + NCDHW transpose store.
// tmp [b][od][oh][w32][144] f32 -> out [4][144][16][16][16] f32.
// Index: b(4) x od(16) x oh(16) x ow(16) x c8(18) = 294,912 = 1152*256.
// ---------------------------------------------------------------------------
__global__ __launch_bounds__(256) void k_lowpass_w(const float* __restrict__ tmp,
                                                   float* __restrict__ out) {
    const int gid = blockIdx.x * 256 + threadIdx.x;   // 1152*256 = 294,912
    const int c8 = gid % 18;
    int r = gid / 18;
    const int ow = r & 15; r >>= 4;
    const int oh = r & 15; r >>= 4;
    const int od = r & 15; r >>= 4;
    const int b  = r;
    const float lw[5] = {0.03208210f, 0.23705644f, 0.46172277f, 0.23705644f, 0.03208210f};
    float a[8];
    #pragma unroll
    for (int j = 0; j < 8; ++j) a[j] = 0.f;
    const float* tb = tmp + ((size_t)(((b * 16 + od) * 16 + oh) * 32)) * 144 + c8 * 8;
    #pragma unroll
    for (int kw = 0; kw < 5; ++kw) {
        const int wz = 2 * ow + kw - 2;
        if (wz < 0 || wz >= 32) continue;
        const float wt1 = lw[kw];
        const float* p = tb + (size_t)wz * 144;
        float4 v0 = *(const float4*)(p);
        float4 v1 = *(const float4*)(p + 4);
        a[0] += wt1 * v0.x; a[1] += wt1 * v0.y; a[2] += wt1 * v0.z; a[3] += wt1 * v0.w;
        a[4] += wt1 * v1.x; a[5] += wt1 * v1.y; a[6] += wt1 * v1.z; a[7] += wt1 * v1.w;
    }
    const int c0 = c8 * 8;
    float* op = out + ((size_t)b * 144 + c0) * 4096 + od * 256 + oh * 16 + ow;
    #pragma unroll
    for (int j = 0; j < 8; ++j) op[(size_t)j * 4096] = a[j];
}

// ---------------------------------------------------------------------------
extern "C" void kernel_launch(void* const* d_in, const int* in_sizes, int n_in,
                              void* d_out, int out_size, void* d_ws, size_t ws_size,
                              hipStream_t stream) {
    const float* x  = (const float*)d_in[0];   // 4*72*32^3
    const float* W  = (const float*)d_in[1];   // 176*72*125
    const float* sb = (const float*)d_in[2];   // 16
    const float* gb = (const float*)d_in[3];   // 32
    float* out = (float*)d_out;                // 4*144*16^3 f32

    char* ws = (char*)d_ws;
    u16* xt = (u16*)(ws);                      // 18,874,368 B
    u16* wt = (u16*)(ws + 18874368);           //  3,379,200 B
    u16* zt = (u16*)(ws + 22253568);           // 37,748,736 B  (total ~60 MB)
    float* tmp = (float*)(ws);                 // reuses xt region after k_conv
                                               // (4*16*16*32*144*4 = 18,874,368 B, exact fit)

    hipLaunchKernelGGL(k_transpose_x, dim3(4096), dim3(256), 0, stream, x, xt);
    hipLaunchKernelGGL(k_prep_w,      dim3(825),  dim3(256), 0, stream, W, wt);
    hipLaunchKernelGGL(k_conv,        dim3(512),  dim3(256), 0, stream, xt, wt, sb, gb, zt);
    hipLaunchKernelGGL(k_lowpass_dh,  dim3(2304), dim3(256), 0, stream, zt, tmp);
    hipLaunchKernelGGL(k_lowpass_w,   dim3(1152), dim3(256), 0, stream, tmp, out);
}